// Round 11
// baseline (639.637 us; speedup 1.0000x reference)
//
#include <hip/hip_runtime.h>
#include <hip/hip_fp16.h>

// Euler neural-ODE scan: B=1024, L=512, S=64, U=32, H=512, dt=0.1.
// 64 blocks x 512 threads (8 waves); block owns 16 batch rows for all steps.
// Round-11 = round-10 + u moved back into LDS z (round-3 pattern):
//   GEMM1 is a single in-place 24-MFMA chain over K=192 (state hi/lo + u
//   hi/lo), initialized from b1v via the MFMA C-operand. Waves 6,7 stage
//   u(t+1) hi/lo into zbuf during P2's pbuf-read latency shadow and own the
//   u prefetch. This deletes the ~40-op u split-pack from all 8 waves' main
//   path (we are VALU-issue-bound; transcendentals are the irreducible rest).
//  * GEMM2 A-form: C2 batch-major, identical layout in every wave; pbuf
//    writes linear b128, P2 reads linear b64 -> zero bank conflicts.
//  * P2 ownership: lane (w; l5=lane>>5, r=lane&31) owns
//      s = (w>>1)*16 + (r>>1), batches b,b+1, b = ((w&1)*2+l5)*4 + 2*(r&1).
//  * Barrier A (P1->P2): plain __syncthreads (no global ops pending).
//    Barrier B (P2->P1): lgkm-only asm barrier (out-stores + u prefetch
//    stay in flight across it).
//  * v_cvt_pkrtz for hi/lo SPLIT sites only; tanh->f16 stays RTN.

typedef _Float16 f16;
typedef __attribute__((ext_vector_type(2))) _Float16 f16x2;
typedef __attribute__((ext_vector_type(8))) _Float16 f16x8;
typedef __attribute__((ext_vector_type(2))) float f32x2;
typedef __attribute__((ext_vector_type(4))) float f32x4;

#define MFMA16(a, b, c) __builtin_amdgcn_mfma_f32_16x16x32_f16((a), (b), (c), 0, 0, 0)

#define BARB() do { asm volatile("s_waitcnt lgkmcnt(0)" ::: "memory"); \
                    __builtin_amdgcn_s_barrier();                      \
                    asm volatile("" ::: "memory"); } while (0)

__device__ __forceinline__ f16x2 pkrtz(float a, float b) {
    return __builtin_bit_cast(f16x2, __builtin_amdgcn_cvt_pkrtz(a, b));
}

__device__ __forceinline__ float tanh_fast(float x) {
    float t = __builtin_amdgcn_exp2f(x * 2.885390081777927f);  // e^{2x}
    float r = __builtin_amdgcn_rcpf(t + 1.0f);
    return __builtin_fmaf(-2.0f, r, 1.0f);
}

__global__ __launch_bounds__(512, 1)
void euler_kernel(const float* __restrict__ init,
                  const float* __restrict__ uin,
                  const float* __restrict__ W1,
                  const float* __restrict__ b1,
                  const float* __restrict__ W2,
                  const float* __restrict__ b2,
                  float* __restrict__ out) {
    const int L = 512, S = 64, U = 32, H = 512;
    const int tid  = threadIdx.x;
    const int lane = tid & 63;
    const int w    = tid >> 6;      // wave 0..7
    const int g    = lane >> 4;     // k-group 0..3
    const int r16  = lane & 15;
    const int b0   = blockIdx.x * 16;

    // z: 6 kk-tiles x 64 chunks x 8 f16; chunk(kk,g',r16') = kk*64+g'*16+r16'.
    // kk 0,1: state_hi; 2,3: state_lo; 4: u_hi; 5: u_lo.
    __shared__ f16   zbuf[384 * 8];          // 6 KB
    // GEMM2 partials, slice ww: dw = (s>>4)*256 + (b>>2)*64 + (s&15)*4 + (b&3)
    __shared__ float pbuf[8 * 1024];         // 32 KB

    // ---- W1^T A-fragments, pi-permuted H-columns (K=192 incl. u rows) ----
    f16x8 W1F[6][4];   // kk 0..3: state (share W1 rows 0..63); 4,5: u (rows 64..95)
    #pragma unroll
    for (int kk = 0; kk < 6; ++kk)
      #pragma unroll
      for (int nf = 0; nf < 4; ++nf) {
          const int hcol = w * 64 + 32 * (nf >> 1) + 8 * (r16 >> 2) + 4 * (nf & 1) + (r16 & 3);
          #pragma unroll
          for (int j = 0; j < 8; ++j) {
              int k  = kk * 32 + g * 8 + j;
              int kr = (k < 128) ? (k & 63) : (64 + (k & 31));
              W1F[kk][nf][j] = (f16)W1[kr * H + hcol];
          }
      }
    f32x4 b1v[4];
    #pragma unroll
    for (int nf = 0; nf < 4; ++nf)
        b1v[nf] = *(const f32x4*)&b1[w * 64 + 32 * (nf >> 1) + 4 * (nf & 1) + 8 * g];

    // ---- W2 fragments: lane holds W2[w*64+a*32+g*8+j][ns*16+r16] ----
    f16x8 W2F[2][4];
    #pragma unroll
    for (int a = 0; a < 2; ++a)
      #pragma unroll
      for (int ns = 0; ns < 4; ++ns)
        #pragma unroll
        for (int j = 0; j < 8; ++j) {
            int k = w * 64 + a * 32 + g * 8 + j;
            W2F[a][ns][j] = (f16)W2[k * S + ns * 16 + r16];
        }

    // ---- P2 ownership: s fixed, batches bP, bP+1 ----
    const int l5 = lane >> 5, r = lane & 31;
    const int sP = (w >> 1) * 16 + (r >> 1);
    const int bP = ((w & 1) * 2 + l5) * 4 + 2 * (r & 1);
    const float b2v = b2[sP];
    // z-write slot (hi): chunk = (sP>>5)*64 + ((sP>>3)&3)*16 + bP, slot sP&7
    const int zci = ((sP >> 5) * 64 + ((sP >> 3) & 3) * 16 + bP) * 8 + (sP & 7);

    f32x2 stateF;
    stateF[0] = init[(size_t)(b0 + bP) * S + sP];
    stateF[1] = init[(size_t)(b0 + bP + 1) * S + sP];
    {
        f16x2 sh = pkrtz(stateF[0], stateF[1]);
        f16x2 sl = pkrtz(stateF[0] - (float)sh[0], stateF[1] - (float)sh[1]);
        zbuf[zci]            = sh[0];
        zbuf[zci + 8]        = sh[1];                      // batch+1 -> chunk+1
        zbuf[zci + 1024]     = sl[0];
        zbuf[zci + 1024 + 8] = sl[1];
    }

    // ---- u staging (waves 6,7): wave 6 = hi @ chunks 256.., wave 7 = lo @ 320..
    const float* uptr = uin + (size_t)(b0 + r16) * L * U + g * 8;
    f32x4 ua0 = (f32x4){0.f, 0.f, 0.f, 0.f}, ua1 = ua0;
    if (w >= 6) {
        f32x4 u0 = *(const f32x4*)uptr;          // u(0)
        f32x4 u1 = *(const f32x4*)(uptr + 4);
        f16x8 uv;
        if (w == 6) {
            f16x2 p01 = pkrtz(u0[0], u0[1]), p23 = pkrtz(u0[2], u0[3]);
            f16x2 p45 = pkrtz(u1[0], u1[1]), p67 = pkrtz(u1[2], u1[3]);
            uv[0]=p01[0]; uv[1]=p01[1]; uv[2]=p23[0]; uv[3]=p23[1];
            uv[4]=p45[0]; uv[5]=p45[1]; uv[6]=p67[0]; uv[7]=p67[1];
            *(f16x8*)&zbuf[(256 + lane) * 8] = uv;
        } else {
            f16x2 p01 = pkrtz(u0[0], u0[1]), p23 = pkrtz(u0[2], u0[3]);
            f16x2 p45 = pkrtz(u1[0], u1[1]), p67 = pkrtz(u1[2], u1[3]);
            f16x2 q01 = pkrtz(u0[0] - (float)p01[0], u0[1] - (float)p01[1]);
            f16x2 q23 = pkrtz(u0[2] - (float)p23[0], u0[3] - (float)p23[1]);
            f16x2 q45 = pkrtz(u1[0] - (float)p45[0], u1[1] - (float)p45[1]);
            f16x2 q67 = pkrtz(u1[2] - (float)p67[0], u1[3] - (float)p67[1]);
            uv[0]=q01[0]; uv[1]=q01[1]; uv[2]=q23[0]; uv[3]=q23[1];
            uv[4]=q45[0]; uv[5]=q45[1]; uv[6]=q67[0]; uv[7]=q67[1];
            *(f16x8*)&zbuf[(320 + lane) * 8] = uv;
        }
        ua0 = *(const f32x4*)(uptr + U);         // prefetch u(1)
        ua1 = *(const f32x4*)(uptr + U + 4);
    }
    __syncthreads();

    #pragma unroll 1
    for (int t = 0; t < L; ++t) {
        // ---- P1: z-read (linear, 6 b128), GEMM1 24-MFMA in-place chain
        //          (b1v as C of the first rank), tanh+pack, GEMM2, pbuf ----
        f16x8 zf[6];
        #pragma unroll
        for (int kk = 0; kk < 6; ++kk)
            zf[kk] = *(const f16x8*)&zbuf[(kk * 64 + lane) * 8];
        f32x4 acc1[4];
        #pragma unroll
        for (int nf = 0; nf < 4; ++nf)
            acc1[nf] = MFMA16(W1F[0][nf], zf[0], b1v[nf]);
        #pragma unroll
        for (int kk = 1; kk < 6; ++kk)
          #pragma unroll
          for (int nf = 0; nf < 4; ++nf)
            acc1[nf] = MFMA16(W1F[kk][nf], zf[kk], acc1[nf]);
        f16x8 hb[2];
        #pragma unroll
        for (int a = 0; a < 2; ++a)
          #pragma unroll
          for (int j8 = 0; j8 < 8; ++j8) {
              int nf = a * 2 + (j8 >> 2), jj = j8 & 3;
              hb[a][j8] = (f16)tanh_fast(acc1[nf][jj]);  // RTN
          }
        f32x4 acc2[4];
        #pragma unroll
        for (int ns = 0; ns < 4; ++ns) acc2[ns] = (f32x4){0.f, 0.f, 0.f, 0.f};
        #pragma unroll
        for (int a = 0; a < 2; ++a)
          #pragma unroll
          for (int ns = 0; ns < 4; ++ns)
            acc2[ns] = MFMA16(hb[a], W2F[a][ns], acc2[ns]);   // A-form: C batch-major
        #pragma unroll
        for (int ns = 0; ns < 4; ++ns)
            *(f32x4*)&pbuf[(w * 256 + ns * 64 + lane) * 4] = acc2[ns];
        __syncthreads();

        // ---- P2: pbuf reads (issued first), u staging in their shadow,
        //          tree reduce, state update, stores, z-write ----
        f32x2 p[8];
        #pragma unroll
        for (int ww = 0; ww < 8; ++ww)
            p[ww] = *(const f32x2*)&pbuf[ww * 1024 + w * 128 + lane * 2];

        if (w >= 6) {  // stage u(t+1) from prefetch regs; prefetch u(t+2)
            if (t + 1 < L) {
                f16x8 uv;
                f16x2 p01 = pkrtz(ua0[0], ua0[1]), p23 = pkrtz(ua0[2], ua0[3]);
                f16x2 p45 = pkrtz(ua1[0], ua1[1]), p67 = pkrtz(ua1[2], ua1[3]);
                if (w == 6) {
                    uv[0]=p01[0]; uv[1]=p01[1]; uv[2]=p23[0]; uv[3]=p23[1];
                    uv[4]=p45[0]; uv[5]=p45[1]; uv[6]=p67[0]; uv[7]=p67[1];
                    *(f16x8*)&zbuf[(256 + lane) * 8] = uv;
                } else {
                    f16x2 q01 = pkrtz(ua0[0] - (float)p01[0], ua0[1] - (float)p01[1]);
                    f16x2 q23 = pkrtz(ua0[2] - (float)p23[0], ua0[3] - (float)p23[1]);
                    f16x2 q45 = pkrtz(ua1[0] - (float)p45[0], ua1[1] - (float)p45[1]);
                    f16x2 q67 = pkrtz(ua1[2] - (float)p67[0], ua1[3] - (float)p67[1]);
                    uv[0]=q01[0]; uv[1]=q01[1]; uv[2]=q23[0]; uv[3]=q23[1];
                    uv[4]=q45[0]; uv[5]=q45[1]; uv[6]=q67[0]; uv[7]=q67[1];
                    *(f16x8*)&zbuf[(320 + lane) * 8] = uv;
                }
            }
            int tp = (t + 2 < L) ? (t + 2) : (L - 1);
            ua0 = *(const f32x4*)(uptr + (size_t)tp * U);
            ua1 = *(const f32x4*)(uptr + (size_t)tp * U + 4);
        }

        f32x2 s01 = (f32x2){0.f, 0.f}, s23 = s01, s45 = s01, s67 = s01;
        #pragma unroll
        for (int j = 0; j < 2; ++j) {
            s01[j] = p[0][j] + p[1][j];
            s23[j] = p[2][j] + p[3][j];
            s45[j] = p[4][j] + p[5][j];
            s67[j] = p[6][j] + p[7][j];
        }
        float d0 = ((s01[0] + s23[0]) + (s45[0] + s67[0])) + b2v;
        float d1 = ((s01[1] + s23[1]) + (s45[1] + s67[1])) + b2v;
        float sn0 = __builtin_fmaf(0.1f, d0, stateF[0]);
        float sn1 = __builtin_fmaf(0.1f, d1, stateF[1]);
        stateF[0] = sn0; stateF[1] = sn1;
        f16x2 sh = pkrtz(sn0, sn1);
        f16x2 sl = pkrtz(sn0 - (float)sh[0], sn1 - (float)sh[1]);
        zbuf[zci]            = sh[0];
        zbuf[zci + 8]        = sh[1];
        zbuf[zci + 1024]     = sl[0];
        zbuf[zci + 1024 + 8] = sl[1];
        out[((size_t)(b0 + bP) * L + t) * S + sP]     = sn0;
        out[((size_t)(b0 + bP + 1) * L + t) * S + sP] = sn1;
        BARB();
    }
}

extern "C" void kernel_launch(void* const* d_in, const int* in_sizes, int n_in,
                              void* d_out, int out_size, void* d_ws, size_t ws_size,
                              hipStream_t stream) {
    const float* init = (const float*)d_in[0];
    const float* uin  = (const float*)d_in[1];
    const float* W1   = (const float*)d_in[2];
    const float* b1   = (const float*)d_in[3];
    const float* W2   = (const float*)d_in[4];
    const float* b2   = (const float*)d_in[5];
    euler_kernel<<<dim3(64), dim3(512), 0, stream>>>(init, uin, W1, b1, W2, b2,
                                                     (float*)d_out);
}